// Round 14
// baseline (421.563 us; speedup 1.0000x reference)
//
#include <hip/hip_runtime.h>
#include <stdint.h>

#define E4M3_MAX 448.0f

typedef float f32x4 __attribute__((ext_vector_type(4)));
typedef int   i32x4 __attribute__((ext_vector_type(4)));
typedef int   i32x8 __attribute__((ext_vector_type(8)));

// ---------------------------------------------------------------------------
// async global -> LDS, 16 bytes per lane. LDS dest stays LINEAR (HW
// constraint); T2 swizzle applied by pre-swizzling the GLOBAL source column
// and swizzling the LDS READ offset with the same involution (rule #21).
// ---------------------------------------------------------------------------
__device__ __forceinline__ void gload_lds16(const void* g, void* l) {
    __builtin_amdgcn_global_load_lds(
        (__attribute__((address_space(1))) void*)(void*)g,
        (__attribute__((address_space(3))) void*)l,
        16, 0, 0);
}

__device__ __forceinline__ uint32_t quant4(float a, float b, float c, float d) {
    a = fminf(fmaxf(a, -E4M3_MAX), E4M3_MAX);
    b = fminf(fmaxf(b, -E4M3_MAX), E4M3_MAX);
    c = fminf(fmaxf(c, -E4M3_MAX), E4M3_MAX);
    d = fminf(fmaxf(d, -E4M3_MAX), E4M3_MAX);
    int q = 0;
    q = __builtin_amdgcn_cvt_pk_fp8_f32(a, b, q, false);
    q = __builtin_amdgcn_cvt_pk_fp8_f32(c, d, q, true);
    return (uint32_t)q;
}

__global__ void quant_x_kernel(const float* __restrict__ x,
                               const float* __restrict__ scale_p,
                               uint4* __restrict__ xq, int n16) {
    const float inv = 1.0f / scale_p[0];
    const int stride = gridDim.x * blockDim.x;
    for (int i = blockIdx.x * blockDim.x + threadIdx.x; i < n16; i += stride) {
        const float4* p = (const float4*)x + (size_t)i * 4;
        float4 v0 = p[0], v1 = p[1], v2 = p[2], v3 = p[3];
        uint4 q;
        q.x = quant4(v0.x * inv, v0.y * inv, v0.z * inv, v0.w * inv);
        q.y = quant4(v1.x * inv, v1.y * inv, v1.z * inv, v1.w * inv);
        q.z = quant4(v2.x * inv, v2.y * inv, v2.z * inv, v2.w * inv);
        q.w = quant4(v3.x * inv, v3.y * inv, v3.z * inv, v3.w * inv);
        xq[i] = q;
    }
}

__global__ void quant_w_kernel(const float* __restrict__ w,
                               const float* __restrict__ wsc,
                               uint4* __restrict__ wq, int n16, int chunk16) {
    const int stride = gridDim.x * blockDim.x;
    for (int i = blockIdx.x * blockDim.x + threadIdx.x; i < n16; i += stride) {
        const float inv = 1.0f / wsc[i / chunk16];
        const float4* p = (const float4*)w + (size_t)i * 4;
        float4 v0 = p[0], v1 = p[1], v2 = p[2], v3 = p[3];
        uint4 q;
        q.x = quant4(v0.x * inv, v0.y * inv, v0.z * inv, v0.w * inv);
        q.y = quant4(v1.x * inv, v1.y * inv, v1.z * inv, v1.w * inv);
        q.z = quant4(v2.x * inv, v2.y * inv, v2.z * inv, v2.w * inv);
        q.w = quant4(v3.x * inv, v3.y * inv, v3.z * inv, v3.w * inv);
        wq[i] = q;
    }
}

__device__ __forceinline__ i32x8 read_frag(const uint8_t* base, int o0, int o1) {
    i32x4 lo = *(const i32x4*)(base + o0);
    i32x4 hi = *(const i32x4*)(base + o1);
    return __builtin_shufflevector(lo, hi, 0, 1, 2, 3, 4, 5, 6, 7);
}

#define MFMA_MX(a, b, c) \
    __builtin_amdgcn_mfma_scale_f32_16x16x128_f8f6f4( \
        (a), (b), (c), 0, 0, 0, 0x7F7F7F7F, 0, 0x7F7F7F7F)

#define WAIT_LGKM(n)                                            \
    do {                                                        \
        asm volatile("s_waitcnt lgkmcnt(" #n ")" ::: "memory"); \
        __builtin_amdgcn_sched_barrier(0);                      \
    } while (0)

// ---------------------------------------------------------------------------
// fp8-MX GEMM, Round-14: 128x128 tile, 4 waves (2Mx2N), wave-tile 64x64,
// acc = 4x4 f32x4 = 64 regs.  Round-6 verified schedule (counted-lgkmcnt
// in-wave pipeline, ONE barrier per K-tile, T2 swizzle, 16x16x128 MX),
// shrunk so LDS = 2 x 32 KB = 64 KB -> TWO blocks co-resident per CU.
// Cross-block overlap: one block's LDS/barrier phases fill the other
// block's MFMA phases (the round-3 mechanism, now with the good schedule).
// Per iter t:
//   top barrier (tile t staged; buf[cur^1] free since t-1's barrier)
//   issue b0..b3 + a0 + a1 (12 ds_read_b128); issue stage(t+1)
//   lgkm(2) [b*,a0 ready, a1 in flight] -> g0 (a0 x b0..3)
//   issue a2; lgkm(2) -> g1 (a1);  issue a3; lgkm(2) -> g2 (a2)
//   lgkm(0) -> g3 (a3)
//   vmcnt(0) (whole MFMA body of slack); s_barrier
// LDS byte map: LDS[row][c] = global[row][c ^ ((row&7)<<4)]  (T2).
// ---------------------------------------------------------------------------
#define BM 128
#define BN 128
#define BKB 128

__global__ __launch_bounds__(256, 2) void gemm_fp8_kernel(
    const uint8_t* __restrict__ Aq, const uint8_t* __restrict__ Bq,
    const float* __restrict__ bias, const float* __restrict__ isp,
    const float* __restrict__ wsc, float* __restrict__ out,
    int M, int N, int K, int ocPerChunk) {
    // [buf][A=0/B=1][128 rows * 128 B]
    __shared__ __align__(16) uint8_t lds[2][2][BM * BKB];

    const int tid  = threadIdx.x;
    const int lane = tid & 63;
    const int wid  = tid >> 6;   // 0..3
    const int wm   = wid >> 1;   // 0..1  (M half)
    const int wn   = wid & 1;    // 0..1  (N half)

    // T1: bijective XCD swizzle (gridDim.x % 8 == 0)
    const int nwg = gridDim.x;
    const int cpx = nwg >> 3;
    const int swz = (blockIdx.x & 7) * cpx + (blockIdx.x >> 3);
    const int nbx = N / BN;
    const int bx  = swz % nbx;
    const int by  = swz / nbx;
    const int m0  = by * BM;
    const int n0  = bx * BN;

    const int lr   = lane & 15;
    const int sw   = (lr & 7) << 4;
    const int off0 = ((lane >> 4) * 32) ^ sw;
    const int off1 = off0 ^ 16;

    f32x4 acc[4][4] = {};

    const int nkt = K / BKB;

    // stage K-tile (k-offset kt) into buffer b: 8 x gload_lds16 per thread
    // idx = i*256 + tid in [0,2048): row = idx>>3 in [0,256);
    // rows 0..127 = A tile rows, rows 128..255 = B tile rows.
    auto stage = [&](int b, int kt) {
#pragma unroll
        for (int i = 0; i < 8; ++i) {
            const int idx = i * 256 + tid;
            const int row = idx >> 3;
            const int col = ((idx & 7) * 16) ^ ((row & 7) << 4);
            const uint8_t* src = (i < 4)
                ? Aq + (size_t)(m0 + row) * K + kt + col
                : Bq + (size_t)(n0 + (row - 128)) * K + kt + col;
            gload_lds16(src, &lds[b][0][0] + idx * 16);
        }
    };

    // prologue: tile 0
    stage(0, 0);
    asm volatile("s_waitcnt vmcnt(0)" ::: "memory");
    __builtin_amdgcn_s_barrier();

    for (int t = 0; t < nkt; ++t) {
        const int cur = t & 1;
        const uint8_t* pa = &lds[cur][0][0] + (wm * 64 + lr) * BKB;
        const uint8_t* pb = &lds[cur][1][0] + (wn * 64 + lr) * BKB;

        // ---- issue B frags + A frags 0,1; then next-tile staging ----
        i32x8 bv[4];
#pragma unroll
        for (int ni = 0; ni < 4; ni++)
            bv[ni] = read_frag(pb + ni * 16 * BKB, off0, off1);
        i32x8 a0 = read_frag(pa,            off0, off1);
        i32x8 a1 = read_frag(pa + 16 * BKB, off0, off1);
        if (t + 1 < nkt) stage(cur ^ 1, (t + 1) * BKB);

        // ---- g0: b*+a0 ready (a1's 2 reads still in flight) ----
        WAIT_LGKM(2);
        __builtin_amdgcn_s_setprio(1);
#pragma unroll
        for (int ni = 0; ni < 4; ni++)
            acc[0][ni] = MFMA_MX(a0, bv[ni], acc[0][ni]);
        __builtin_amdgcn_s_setprio(0);

        // ---- g1: issue a2, wait a1 ----
        i32x8 a2 = read_frag(pa + 32 * BKB, off0, off1);
        WAIT_LGKM(2);
        __builtin_amdgcn_s_setprio(1);
#pragma unroll
        for (int ni = 0; ni < 4; ni++)
            acc[1][ni] = MFMA_MX(a1, bv[ni], acc[1][ni]);
        __builtin_amdgcn_s_setprio(0);

        // ---- g2: issue a3, wait a2 ----
        i32x8 a3 = read_frag(pa + 48 * BKB, off0, off1);
        WAIT_LGKM(2);
        __builtin_amdgcn_s_setprio(1);
#pragma unroll
        for (int ni = 0; ni < 4; ni++)
            acc[2][ni] = MFMA_MX(a2, bv[ni], acc[2][ni]);
        __builtin_amdgcn_s_setprio(0);

        // ---- g3: wait a3 (all tile-t reads retired after this) ----
        WAIT_LGKM(0);
        __builtin_amdgcn_s_setprio(1);
#pragma unroll
        for (int ni = 0; ni < 4; ni++)
            acc[3][ni] = MFMA_MX(a3, bv[ni], acc[3][ni]);
        __builtin_amdgcn_s_setprio(0);

        // ---- end of iter: tile t+1 must be fully in LDS before next top ----
        asm volatile("s_waitcnt vmcnt(0)" ::: "memory");
        __builtin_amdgcn_s_barrier();
    }

    // ---- epilogue: dequant + bias (C/D: col=lane&15, row=(lane>>4)*4+j) ----
    const float is = isp[0];
#pragma unroll
    for (int ni = 0; ni < 4; ni++) {
        const int cidx = n0 + wn * 64 + ni * 16 + lr;
        const float sc = is * wsc[cidx / ocPerChunk];
        const float bs = bias[cidx];
#pragma unroll
        for (int mi = 0; mi < 4; mi++) {
            const int rbase = m0 + wm * 64 + mi * 16 + (lane >> 4) * 4;
#pragma unroll
            for (int j = 0; j < 4; j++)
                out[(size_t)(rbase + j) * N + cidx] = acc[mi][ni][j] * sc + bs;
        }
    }
}

// ---------------------------------------------------------------------------
extern "C" void kernel_launch(void* const* d_in, const int* in_sizes, int n_in,
                              void* d_out, int out_size, void* d_ws, size_t ws_size,
                              hipStream_t stream) {
    const float* x        = (const float*)d_in[0];
    const float* w        = (const float*)d_in[1];
    const float* bias     = (const float*)d_in[2];
    const float* in_scale = (const float*)d_in[3];
    const float* w_scales = (const float*)d_in[4];
    float* out = (float*)d_out;

    const int N = in_sizes[2];               // 4096
    const int K = in_sizes[1] / N;           // 4096
    const int M = in_sizes[0] / K;           // 16384
    const int CHUNKS = in_sizes[4];          // 4
    const int ocPerChunk = N / CHUNKS;       // 1024

    uint8_t* xq = (uint8_t*)d_ws;            // M*K bytes
    uint8_t* wq = xq + (size_t)M * K;        // N*K bytes

    const int xn16 = (int)(((size_t)M * K) / 16);
    const int wn16 = (int)(((size_t)N * K) / 16);
    const int chunk16 = (N / CHUNKS) * K / 16;

    quant_x_kernel<<<2048, 256, 0, stream>>>(x, in_scale, (uint4*)xq, xn16);
    quant_w_kernel<<<2048, 256, 0, stream>>>(w, w_scales, (uint4*)wq, wn16, chunk16);

    const int nblk = (M / BM) * (N / BN);    // 128 * 32 = 4096
    gemm_fp8_kernel<<<dim3(nblk), 256, 0, stream>>>(xq, wq, bias, in_scale,
                                                    w_scales, out, M, N, K,
                                                    ocPerChunk);
}

// Round 15
// 372.828 us; speedup vs baseline: 1.1307x; 1.1307x over previous
//
#include <hip/hip_runtime.h>
#include <stdint.h>

#define E4M3_MAX 448.0f

typedef float f32x4 __attribute__((ext_vector_type(4)));
typedef int   i32x4 __attribute__((ext_vector_type(4)));
typedef int   i32x8 __attribute__((ext_vector_type(8)));

// ---------------------------------------------------------------------------
// async global -> LDS, 16 bytes per lane. LDS dest stays LINEAR (HW
// constraint); T2 swizzle applied by pre-swizzling the GLOBAL source column
// and swizzling the LDS READ offset with the same involution (rule #21).
// ---------------------------------------------------------------------------
__device__ __forceinline__ void gload_lds16(const void* g, void* l) {
    __builtin_amdgcn_global_load_lds(
        (__attribute__((address_space(1))) void*)(void*)g,
        (__attribute__((address_space(3))) void*)l,
        16, 0, 0);
}

__device__ __forceinline__ uint32_t quant4(float a, float b, float c, float d) {
    a = fminf(fmaxf(a, -E4M3_MAX), E4M3_MAX);
    b = fminf(fmaxf(b, -E4M3_MAX), E4M3_MAX);
    c = fminf(fmaxf(c, -E4M3_MAX), E4M3_MAX);
    d = fminf(fmaxf(d, -E4M3_MAX), E4M3_MAX);
    int q = 0;
    q = __builtin_amdgcn_cvt_pk_fp8_f32(a, b, q, false);
    q = __builtin_amdgcn_cvt_pk_fp8_f32(c, d, q, true);
    return (uint32_t)q;
}

__global__ void quant_x_kernel(const float* __restrict__ x,
                               const float* __restrict__ scale_p,
                               uint4* __restrict__ xq, int n16) {
    const float inv = 1.0f / scale_p[0];
    const int stride = gridDim.x * blockDim.x;
    for (int i = blockIdx.x * blockDim.x + threadIdx.x; i < n16; i += stride) {
        const float4* p = (const float4*)x + (size_t)i * 4;
        float4 v0 = p[0], v1 = p[1], v2 = p[2], v3 = p[3];
        uint4 q;
        q.x = quant4(v0.x * inv, v0.y * inv, v0.z * inv, v0.w * inv);
        q.y = quant4(v1.x * inv, v1.y * inv, v1.z * inv, v1.w * inv);
        q.z = quant4(v2.x * inv, v2.y * inv, v2.z * inv, v2.w * inv);
        q.w = quant4(v3.x * inv, v3.y * inv, v3.z * inv, v3.w * inv);
        xq[i] = q;
    }
}

__global__ void quant_w_kernel(const float* __restrict__ w,
                               const float* __restrict__ wsc,
                               uint4* __restrict__ wq, int n16, int chunk16) {
    const int stride = gridDim.x * blockDim.x;
    for (int i = blockIdx.x * blockDim.x + threadIdx.x; i < n16; i += stride) {
        const float inv = 1.0f / wsc[i / chunk16];
        const float4* p = (const float4*)w + (size_t)i * 4;
        float4 v0 = p[0], v1 = p[1], v2 = p[2], v3 = p[3];
        uint4 q;
        q.x = quant4(v0.x * inv, v0.y * inv, v0.z * inv, v0.w * inv);
        q.y = quant4(v1.x * inv, v1.y * inv, v1.z * inv, v1.w * inv);
        q.z = quant4(v2.x * inv, v2.y * inv, v2.z * inv, v2.w * inv);
        q.w = quant4(v3.x * inv, v3.y * inv, v3.z * inv, v3.w * inv);
        wq[i] = q;
    }
}

__device__ __forceinline__ i32x8 read_frag(const uint8_t* base, int o0, int o1) {
    i32x4 lo = *(const i32x4*)(base + o0);
    i32x4 hi = *(const i32x4*)(base + o1);
    return __builtin_shufflevector(lo, hi, 0, 1, 2, 3, 4, 5, 6, 7);
}

#define MFMA_MX(a, b, c) \
    __builtin_amdgcn_mfma_scale_f32_16x16x128_f8f6f4( \
        (a), (b), (c), 0, 0, 0, 0x7F7F7F7F, 0, 0x7F7F7F7F)

#define WAIT_LGKM(n)                                          \
    do {                                                      \
        asm volatile("s_waitcnt lgkmcnt(" #n ")" ::: "memory"); \
        __builtin_amdgcn_sched_barrier(0);                    \
    } while (0)

// ---------------------------------------------------------------------------
// fp8-MX GEMM, 256x256 tile, 8 waves (2Mx4N), wave-tile 128x64.
// BKB=128 bytes = one K=128 MFMA step.  Round-6 schedule (verified best
// across 14 rounds of structural exploration):
// counted-lgkmcnt register pipeline -> LDS pipe overlaps matrix pipe
// within each wave:
//   top barrier (tile t staged, buf[cur^1] free)
//   issue B(8 b128) + pair0(4) + pair1(4); issue stage(t+1) into cur^1
//   lgkmcnt(4)  -> B+pair0 ready, pair1 in flight   -> MFMA g0
//   issue pair2; lgkmcnt(4) -> pair1 ready          -> MFMA g1
//   issue pair3; lgkmcnt(4) -> pair2 ready          -> MFMA g2
//   lgkmcnt(0)  -> pair3 ready                      -> MFMA g3
//   vmcnt(0) (3+ phases of slack since stage issue); s_barrier
// ONE barrier per K-tile. lgkmcnt(0) before g3 retires all tile-t reads
// before any wave passes the barrier -> stage(t+1) WAR-safe.
// LDS byte map: LDS[row][c] = global[row][c ^ ((row&7)<<4)]  (T2).
// ---------------------------------------------------------------------------
#define BM 256
#define BN 256
#define BKB 128

__global__ __launch_bounds__(512, 2) void gemm_fp8_kernel(
    const uint8_t* __restrict__ Aq, const uint8_t* __restrict__ Bq,
    const float* __restrict__ bias, const float* __restrict__ isp,
    const float* __restrict__ wsc, float* __restrict__ out,
    int M, int N, int K, int ocPerChunk) {
    // [buf][A=0/B=1][256 rows * 128 B]
    __shared__ __align__(16) uint8_t lds[2][2][BM * BKB];

    const int tid  = threadIdx.x;
    const int lane = tid & 63;
    const int wid  = tid >> 6;   // 0..7
    const int wm   = wid >> 2;   // 0..1  (M half)
    const int wn   = wid & 3;    // 0..3  (N quarter)

    // T1: bijective XCD swizzle (gridDim.x % 8 == 0)
    const int nwg = gridDim.x;
    const int cpx = nwg >> 3;
    const int swz = (blockIdx.x & 7) * cpx + (blockIdx.x >> 3);
    const int nbx = N / BN;
    const int bx  = swz % nbx;
    const int by  = swz / nbx;
    const int m0  = by * BM;
    const int n0  = bx * BN;

    const int lr   = lane & 15;
    const int sw   = (lr & 7) << 4;
    const int off0 = ((lane >> 4) * 32) ^ sw;
    const int off1 = off0 ^ 16;

    f32x4 acc[8][4] = {};

    const int nkt = K / BKB;

    // stage K-tile (k-offset kt) into buffer b: 8 x gload_lds16 per thread
    auto stage = [&](int b, int kt) {
#pragma unroll
        for (int i = 0; i < 8; ++i) {
            const int idx = i * 512 + tid;                 // 0..4095
            const int row = idx >> 3;                      // 0..511
            const int col = ((idx & 7) * 16) ^ ((row & 7) << 4);
            const uint8_t* src = (i < 4)
                ? Aq + (size_t)(m0 + row) * K + kt + col
                : Bq + (size_t)(n0 + (row - 256)) * K + kt + col;
            gload_lds16(src, &lds[b][0][0] + idx * 16);
        }
    };

    // prologue: tile 0
    stage(0, 0);
    asm volatile("s_waitcnt vmcnt(0)" ::: "memory");
    __builtin_amdgcn_s_barrier();

    for (int t = 0; t < nkt; ++t) {
        const int cur = t & 1;
        const uint8_t* pa = &lds[cur][0][0] + (wm * 128 + lr) * BKB;
        const uint8_t* pb = &lds[cur][1][0] + (wn * 64  + lr) * BKB;

        // ---- issue B frags + A pairs 0,1; then next-tile staging ----
        i32x8 bv[4];
#pragma unroll
        for (int ni = 0; ni < 4; ni++)
            bv[ni] = read_frag(pb + ni * 16 * BKB, off0, off1);
        i32x8 a0 = read_frag(pa,            off0, off1);
        i32x8 a1 = read_frag(pa + 16 * BKB, off0, off1);
        i32x8 a2 = read_frag(pa + 32 * BKB, off0, off1);
        i32x8 a3 = read_frag(pa + 48 * BKB, off0, off1);
        if (t + 1 < nkt) stage(cur ^ 1, (t + 1) * BKB);

        // ---- g0: B + pair0 ready (pair1's 4 reads still in flight) ----
        WAIT_LGKM(4);
        __builtin_amdgcn_s_setprio(1);
#pragma unroll
        for (int ni = 0; ni < 4; ni++) {
            acc[0][ni] = MFMA_MX(a0, bv[ni], acc[0][ni]);
            acc[1][ni] = MFMA_MX(a1, bv[ni], acc[1][ni]);
        }
        __builtin_amdgcn_s_setprio(0);

        // ---- g1: issue pair2, wait pair1 ----
        i32x8 a4 = read_frag(pa + 64 * BKB, off0, off1);
        i32x8 a5 = read_frag(pa + 80 * BKB, off0, off1);
        WAIT_LGKM(4);
        __builtin_amdgcn_s_setprio(1);
#pragma unroll
        for (int ni = 0; ni < 4; ni++) {
            acc[2][ni] = MFMA_MX(a2, bv[ni], acc[2][ni]);
            acc[3][ni] = MFMA_MX(a3, bv[ni], acc[3][ni]);
        }
        __builtin_amdgcn_s_setprio(0);

        // ---- g2: issue pair3, wait pair2 ----
        i32x8 a6 = read_frag(pa + 96 * BKB,  off0, off1);
        i32x8 a7 = read_frag(pa + 112 * BKB, off0, off1);
        WAIT_LGKM(4);
        __builtin_amdgcn_s_setprio(1);
#pragma unroll
        for (int ni = 0; ni < 4; ni++) {
            acc[4][ni] = MFMA_MX(a4, bv[ni], acc[4][ni]);
            acc[5][ni] = MFMA_MX(a5, bv[ni], acc[5][ni]);
        }
        __builtin_amdgcn_s_setprio(0);

        // ---- g3: wait pair3 (all tile-t reads retired after this) ----
        WAIT_LGKM(0);
        __builtin_amdgcn_s_setprio(1);
#pragma unroll
        for (int ni = 0; ni < 4; ni++) {
            acc[6][ni] = MFMA_MX(a6, bv[ni], acc[6][ni]);
            acc[7][ni] = MFMA_MX(a7, bv[ni], acc[7][ni]);
        }
        __builtin_amdgcn_s_setprio(0);

        // ---- end of iter: tile t+1 must be fully in LDS before next top ----
        asm volatile("s_waitcnt vmcnt(0)" ::: "memory");
        __builtin_amdgcn_s_barrier();
    }

    // ---- epilogue: dequant + bias (C/D: col=lane&15, row=(lane>>4)*4+j) ----
    const float is = isp[0];
#pragma unroll
    for (int ni = 0; ni < 4; ni++) {
        const int cidx = n0 + wn * 64 + ni * 16 + lr;
        const float sc = is * wsc[cidx / ocPerChunk];
        const float bs = bias[cidx];
#pragma unroll
        for (int mi = 0; mi < 8; mi++) {
            const int rbase = m0 + wm * 128 + mi * 16 + (lane >> 4) * 4;
#pragma unroll
            for (int j = 0; j < 4; j++)
                out[(size_t)(rbase + j) * N + cidx] = acc[mi][ni][j] * sc + bs;
        }
    }
}

// ---------------------------------------------------------------------------
extern "C" void kernel_launch(void* const* d_in, const int* in_sizes, int n_in,
                              void* d_out, int out_size, void* d_ws, size_t ws_size,
                              hipStream_t stream) {
    const float* x        = (const float*)d_in[0];
    const float* w        = (const float*)d_in[1];
    const float* bias     = (const float*)d_in[2];
    const float* in_scale = (const float*)d_in[3];
    const float* w_scales = (const float*)d_in[4];
    float* out = (float*)d_out;

    const int N = in_sizes[2];               // 4096
    const int K = in_sizes[1] / N;           // 4096
    const int M = in_sizes[0] / K;           // 16384
    const int CHUNKS = in_sizes[4];          // 4
    const int ocPerChunk = N / CHUNKS;       // 1024

    uint8_t* xq = (uint8_t*)d_ws;            // M*K bytes
    uint8_t* wq = xq + (size_t)M * K;        // N*K bytes

    const int xn16 = (int)(((size_t)M * K) / 16);
    const int wn16 = (int)(((size_t)N * K) / 16);
    const int chunk16 = (N / CHUNKS) * K / 16;

    quant_x_kernel<<<2048, 256, 0, stream>>>(x, in_scale, (uint4*)xq, xn16);
    quant_w_kernel<<<2048, 256, 0, stream>>>(w, w_scales, (uint4*)wq, wn16, chunk16);

    const int nblk = (M / BM) * (N / BN);    // 64 * 16 = 1024
    gemm_fp8_kernel<<<dim3(nblk), 512, 0, stream>>>(xq, wq, bias, in_scale,
                                                    w_scales, out, M, N, K,
                                                    ocPerChunk);
}